// Round 11
// baseline (819.390 us; speedup 1.0000x reference)
//
#include <hip/hip_runtime.h>

#define TOKENS 8192
#define DIM 1024
#define NEXP 8
#define FDIM 4096

typedef __bf16 bf16x8 __attribute__((ext_vector_type(8)));
typedef float f32x4 __attribute__((ext_vector_type(4)));
typedef float f32x16 __attribute__((ext_vector_type(16)));

__device__ __forceinline__ unsigned short f2bf(float f) {
  unsigned u = __builtin_bit_cast(unsigned, f);
  u += 0x7fffu + ((u >> 16) & 1u);
  return (unsigned short)(u >> 16);
}

__device__ __forceinline__ float bf2f(unsigned short s) {
  unsigned u = (unsigned)s << 16;
  return __builtin_bit_cast(float, u);
}

__device__ __forceinline__ void gload16(const void* g, void* l) {
  __builtin_amdgcn_global_load_lds(
      (const __attribute__((address_space(1))) unsigned int*)g,
      (__attribute__((address_space(3))) unsigned int*)l, 16, 0, 0);
}

// ---------------- router ----------------
__global__ void zero_counts_kernel(int* counts) {
  if (threadIdx.x < NEXP) counts[threadIdx.x] = 0;
}

// offs + chunked XCD work tables for 256(row)x128(col) tiles.
// Chunk = 4 m-tiles x 4 n-tiles of one expert = 16 blocks.
__global__ void scan_kernel(const int* counts, int* offs, int* nchk,
                            int* chunks0, int* chunks1) {
  if (threadIdx.x == 0) {
    int s = 0;
    for (int e = 0; e < NEXP; ++e) { offs[e] = s; s += counts[e]; }
    offs[NEXP] = s;
    int nc0 = 0, nc1 = 0;
    for (int e = 0; e < NEXP; ++e) {
      const int mt = (counts[e] + 255) >> 8;   // 256-row tiles
      for (int mc = 0; mc < mt; mc += 4) {
        for (int n4 = 0; n4 < 32; n4 += 4)     // MODE0: 4096/128 = 32 n-tiles
          chunks0[nc0++] = (e << 16) | (mc << 8) | n4;
        for (int n4 = 0; n4 < 8; n4 += 4)      // MODE1: 1024/128 = 8 n-tiles
          chunks1[nc1++] = (e << 16) | (mc << 8) | n4;
      }
    }
    nchk[0] = nc0;
    nchk[1] = nc1;
  }
}

__global__ void router_kernel(const float* __restrict__ hs,
                              const float* __restrict__ gw,
                              const float* __restrict__ gb,
                              int* __restrict__ counts,
                              int* __restrict__ tok_idx,
                              float* __restrict__ tok_w,
                              unsigned int* __restrict__ slotinfo,
                              unsigned short* __restrict__ hs_bf) {
  const int lane = threadIdx.x & 63;
  const int wid = threadIdx.x >> 6;
  const int t = blockIdx.x * 4 + wid;
  const float* row = hs + (size_t)t * DIM;

  float x[16];
  const float4* r4 = (const float4*)(row + lane * 16);
#pragma unroll
  for (int i = 0; i < 4; ++i) {
    float4 v = r4[i];
    x[i * 4 + 0] = v.x; x[i * 4 + 1] = v.y; x[i * 4 + 2] = v.z; x[i * 4 + 3] = v.w;
  }

  float acc[8];
#pragma unroll
  for (int e = 0; e < 8; ++e) acc[e] = 0.f;
#pragma unroll
  for (int i = 0; i < 16; ++i) {
    const int d = lane * 16 + i;
    const float4* g4 = (const float4*)(gw + (size_t)d * 8);
    float4 g0 = g4[0], g1 = g4[1];
    const float xv = x[i];
    acc[0] += xv * g0.x; acc[1] += xv * g0.y; acc[2] += xv * g0.z; acc[3] += xv * g0.w;
    acc[4] += xv * g1.x; acc[5] += xv * g1.y; acc[6] += xv * g1.z; acc[7] += xv * g1.w;
  }
#pragma unroll
  for (int sh = 1; sh < 64; sh <<= 1) {
#pragma unroll
    for (int e = 0; e < 8; ++e) acc[e] += __shfl_xor(acc[e], sh, 64);
  }
#pragma unroll
  for (int e = 0; e < 8; ++e) acc[e] += gb[e];

  float mx = acc[0];
#pragma unroll
  for (int e = 1; e < 8; ++e) mx = fmaxf(mx, acc[e]);
  float p[8];
  float sum = 0.f;
#pragma unroll
  for (int e = 0; e < 8; ++e) { p[e] = __expf(acc[e] - mx); sum += p[e]; }
  const float inv = 1.0f / sum;

  int i0 = 0; float b0 = p[0];
#pragma unroll
  for (int e = 1; e < 8; ++e) if (p[e] > b0) { b0 = p[e]; i0 = e; }
  int i1 = -1; float b1v = -1.f;
#pragma unroll
  for (int e = 0; e < 8; ++e) if (e != i0 && p[e] > b1v) { b1v = p[e]; i1 = e; }

  if (lane == 0) {
    int pos0 = atomicAdd(&counts[i0], 1);
    tok_idx[i0 * TOKENS + pos0] = t;
    tok_w[i0 * TOKENS + pos0] = b0 * inv;
    int pos1 = atomicAdd(&counts[i1], 1);
    tok_idx[i1 * TOKENS + pos1] = t;
    tok_w[i1 * TOKENS + pos1] = b1v * inv;
    // pack both slots: e0:3 | p0:13 | e1:3 | p1:13
    slotinfo[t] = ((unsigned)i0 << 29) | ((unsigned)pos0 << 16) |
                  ((unsigned)i1 << 13) | (unsigned)pos1;
  }

  unsigned short us[16];
#pragma unroll
  for (int i = 0; i < 16; ++i) us[i] = f2bf(x[i]);
  uint4 o0, o1;
  o0.x = (unsigned)us[0] | ((unsigned)us[1] << 16);
  o0.y = (unsigned)us[2] | ((unsigned)us[3] << 16);
  o0.z = (unsigned)us[4] | ((unsigned)us[5] << 16);
  o0.w = (unsigned)us[6] | ((unsigned)us[7] << 16);
  o1.x = (unsigned)us[8] | ((unsigned)us[9] << 16);
  o1.y = (unsigned)us[10] | ((unsigned)us[11] << 16);
  o1.z = (unsigned)us[12] | ((unsigned)us[13] << 16);
  o1.w = (unsigned)us[14] | ((unsigned)us[15] << 16);
  uint4* dst = (uint4*)(hs_bf + (size_t)t * DIM + lane * 16);
  dst[0] = o0;
  dst[1] = o1;
}

// ---------------- merged transpose+cast for w1 and w2 in one launch ----------------
__global__ void cast_transpose_all(const float* __restrict__ w1,
                                   unsigned short* __restrict__ w1t,
                                   const float* __restrict__ w2,
                                   unsigned short* __restrict__ w2t) {
  __shared__ float tile[64][65];
  const int L = blockIdx.x;
  const float* src;
  unsigned short* dstp;
  int R, C, bi;
  if (L < 8192) { src = w1; dstp = w1t; R = DIM;  C = FDIM; bi = L; }
  else          { src = w2; dstp = w2t; R = FDIM; C = DIM;  bi = L - 8192; }
  const int nx = C >> 6;
  const int e = bi >> 10;
  const int w = bi & 1023;
  const int by = w / nx, bx = w % nx;
  const int r0 = by * 64, c0 = bx * 64;
  const float* s = src + (size_t)e * R * C;
  unsigned int* d = (unsigned int*)(dstp + (size_t)e * R * C);

#pragma unroll
  for (int i = 0; i < 16; ++i) {
    const int idx = threadIdx.x + i * 256;
    const int r = idx >> 6;
    const int c = idx & 63;
    tile[r][c] = s[(size_t)(r0 + r) * C + (c0 + c)];
  }
  __syncthreads();
#pragma unroll
  for (int i = 0; i < 8; ++i) {
    const int idx = threadIdx.x + i * 256;
    const int c = idx >> 5;
    const int r = (idx & 31) * 2;
    unsigned pk = (unsigned)f2bf(tile[r][c]) | ((unsigned)f2bf(tile[r + 1][c]) << 16);
    d[((size_t)(c0 + c) * R + (r0 + r)) >> 1] = pk;
  }
}

// ---------------- grouped GEMM: 256x128 block tile, 128x64 per wave, BK=32 ----------------
// Double-buffered 2x24 KiB LDS, distance-1 prefetch, counted vmcnt(6).
// Per wave per kq: 4 A-frag + 2 B-frag ds_read_b128 feed 8 mfma_32x32x16
// -> 43.7 FLOP per LDS-read-byte (1.37x less LDS traffic than 64x64 waves).
// Buffer b at b*24576: A 256 rows x 64B at +0, B 128 rows x 64B at +16384.
template<int MODE, int K, int N>
__global__ __launch_bounds__(256, 2)
void moe_gemm(const unsigned short* __restrict__ Abase,
              const unsigned short* __restrict__ Bbase,
              const float* __restrict__ bias,
              const int* __restrict__ counts,
              const int* __restrict__ offs,
              const int* __restrict__ tok_idx,
              const int* __restrict__ chunktab,
              const int* __restrict__ nchk,
              unsigned short* __restrict__ dst) {
  constexpr int NS = K / 32;
  __shared__ __align__(16) unsigned char sm[49152];

  // ---- chunked XCD-aware work decode (16 blocks = 4m x 4n per chunk) ----
  const int L = blockIdx.x;
  const int xk = L & 7;
  const int tt = L >> 3;
  const int g = (tt >> 4) * 8 + xk;
  if (g >= nchk[MODE]) return;
  const int within = tt & 15;
  const int cd = chunktab[g];
  const int e = cd >> 16;
  const int cnt = counts[e];
  const int m0 = (((cd >> 8) & 255) + (within >> 2)) * 256;
  if (m0 >= cnt) return;
  const int n0 = ((cd & 255) + (within & 3)) * 128;
  const int goff = offs[e];

  const int tid = threadIdx.x;
  const int lane = tid & 63;
  const int wid = tid >> 6;
  const int wm = wid >> 1;   // 0..1 : 128-row M band
  const int wn = wid & 1;    // 0..1 : 64-col N band
  const int l31 = lane & 31;
  const int lh = lane >> 5;  // 0..1 : 8-elem K-half within a 16-wide k-quarter

  // ---- staging source pointers (A rows trow+64j, B rows trow+64j; swizzled chunk) ----
  const int trow = tid >> 2;
  const int tswz = (tid & 3) ^ ((trow >> 1) & 3);   // invariant under +64 row shifts
  const unsigned char* Bexp = (const unsigned char*)(Bbase + (size_t)e * K * N);

  const unsigned char* pA[4];
#pragma unroll
  for (int j = 0; j < 4; ++j) {
    int gr = m0 + trow + j * 64;
    if (gr > cnt - 1) gr = cnt - 1;
    size_t rowA;
    if (MODE == 0) rowA = (size_t)tok_idx[e * TOKENS + gr] * K;
    else           rowA = (size_t)(goff + gr) * K;
    pA[j] = (const unsigned char*)(Abase + rowA) + tswz * 16;
  }
  const unsigned char* pB0 = Bexp + (size_t)(n0 + trow) * (K * 2) + tswz * 16;
  const unsigned char* pB1 = Bexp + (size_t)(n0 + trow + 64) * (K * 2) + tswz * 16;

  // ---- LDS read bases (within 24 KiB buffer) ----
  // stored chunk for (kq,lh) = (kq*2+lh) ^ sw ; kq=1 addr = kq=0 addr ^ 32.
  const int sw = (l31 >> 1) & 3;
  const int cE = lh ^ sw;
  const int aB = wm * 8192 + l31 * 64 + cE * 16;           // + mb*2048
  const int bB = 16384 + wn * 4096 + l31 * 64 + cE * 16;   // + nb*2048
  const unsigned char* smc = (const unsigned char*)sm;
  unsigned char* smw = (unsigned char*)sm + tid * 16;

  f32x16 acc[4][2];
#pragma unroll
  for (int mb = 0; mb < 4; ++mb)
#pragma unroll
    for (int nb = 0; nb < 2; ++nb)
#pragma unroll
      for (int r = 0; r < 16; ++r) acc[mb][nb][r] = 0.f;

  // ---- prologue: stage step 0 into buffer 0 (6 loads/thread) ----
#pragma unroll
  for (int j = 0; j < 4; ++j) gload16(pA[j], smw + j * 4096);
  gload16(pB0, smw + 16384);
  gload16(pB1, smw + 20480);
#pragma unroll
  for (int j = 0; j < 4; ++j) pA[j] += 64;
  pB0 += 64; pB1 += 64;

#pragma unroll 1
  for (int st = 0; st < NS; ++st) {
    const int cs = (st & 1) ? 24576 : 0;
    const int ns = (st & 1) ? 0 : 24576;
    if (st < NS - 1) {
      // prefetch next step into the other buffer (its readers drained at the
      // lgkm(0)+barrier that ended step st-1)
#pragma unroll
      for (int j = 0; j < 4; ++j) gload16(pA[j], smw + ns + j * 4096);
      gload16(pB0, smw + ns + 16384);
      gload16(pB1, smw + ns + 20480);
#pragma unroll
      for (int j = 0; j < 4; ++j) pA[j] += 64;
      pB0 += 64; pB1 += 64;
      asm volatile("s_waitcnt vmcnt(6)" ::: "memory");  // step st's 6 loads landed
    } else {
      asm volatile("s_waitcnt vmcnt(0)" ::: "memory");
    }
    __builtin_amdgcn_s_barrier();
    __builtin_amdgcn_sched_barrier(0);
#pragma unroll
    for (int kq = 0; kq < 2; ++kq) {
      const int ko = kq << 5;  // chunk-bit XOR: kq1 chunk = kq0 chunk ^ 2
      bf16x8 a0 = *(const bf16x8*)(smc + cs + ((aB + 0)    ^ ko));
      bf16x8 a1 = *(const bf16x8*)(smc + cs + ((aB + 2048) ^ ko));
      bf16x8 a2 = *(const bf16x8*)(smc + cs + ((aB + 4096) ^ ko));
      bf16x8 a3 = *(const bf16x8*)(smc + cs + ((aB + 6144) ^ ko));
      bf16x8 b0 = *(const bf16x8*)(smc + cs + ((bB + 0)    ^ ko));
      bf16x8 b1 = *(const bf16x8*)(smc + cs + ((bB + 2048) ^ ko));
      acc[0][0] = __builtin_amdgcn_mfma_f32_32x32x16_bf16(a0, b0, acc[0][0], 0, 0, 0);
      acc[0][1] = __builtin_amdgcn_mfma_f32_32x32x16_bf16(a0, b1, acc[0][1], 0, 0, 0);
      acc[1][0] = __builtin_amdgcn_mfma_f32_32x32x16_bf16(a1, b0, acc[1][0], 0, 0, 0);
      acc[1][1] = __builtin_amdgcn_mfma_f32_32x32x16_bf16(a1, b1, acc[1][1], 0, 0, 0);
      acc[2][0] = __builtin_amdgcn_mfma_f32_32x32x16_bf16(a2, b0, acc[2][0], 0, 0, 0);
      acc[2][1] = __builtin_amdgcn_mfma_f32_32x32x16_bf16(a2, b1, acc[2][1], 0, 0, 0);
      acc[3][0] = __builtin_amdgcn_mfma_f32_32x32x16_bf16(a3, b0, acc[3][0], 0, 0, 0);
      acc[3][1] = __builtin_amdgcn_mfma_f32_32x32x16_bf16(a3, b1, acc[3][1], 0, 0, 0);
    }
    __builtin_amdgcn_sched_barrier(0);
    asm volatile("s_waitcnt lgkmcnt(0)" ::: "memory");
    __builtin_amdgcn_s_barrier();
  }

  // ---- epilogue: C/D map col=lane&31, row=(reg&3)+8*(reg>>2)+4*(lane>>5) ----
#pragma unroll
  for (int nb = 0; nb < 2; ++nb) {
    const int fcol = n0 + wn * 64 + nb * 32 + l31;
    const float bv = bias[e * N + fcol];
#pragma unroll
    for (int mb = 0; mb < 4; ++mb) {
#pragma unroll
      for (int r = 0; r < 16; ++r) {
        const int ml = wm * 128 + mb * 32 + (r & 3) + 8 * (r >> 2) + 4 * lh;
        const int gm = m0 + ml;
        if (gm < cnt) {
          float v = acc[mb][nb][r] + bv;
          if (MODE == 0) {
            const float u = 0.7978845608028654f * (v + 0.044715f * v * v * v);
            const float th = 1.0f - 2.0f / (1.0f + __expf(2.0f * u));
            v = 0.5f * v * (1.0f + th);
          }
          dst[(size_t)(goff + gm) * N + fcol] = f2bf(v);
        }
      }
    }
  }
}

// ---------------- fused combine + residual + layernorm ----------------
__global__ void ln_combine_kernel(const unsigned short* __restrict__ y_buf,
                                  const float* __restrict__ in_t,
                                  const int* __restrict__ offs,
                                  const unsigned int* __restrict__ slotinfo,
                                  const float* __restrict__ tok_w,
                                  const float* __restrict__ gamma,
                                  const float* __restrict__ beta,
                                  float* __restrict__ out) {
  const int lane = threadIdx.x & 63;
  const int wid = threadIdx.x >> 6;
  const int t = blockIdx.x * 4 + wid;

  const unsigned s = slotinfo[t];
  const int e0 = s >> 29, p0 = (s >> 16) & 8191;
  const int e1 = (s >> 13) & 7, p1 = s & 8191;
  const float w0 = tok_w[e0 * TOKENS + p0];
  const float w1 = tok_w[e1 * TOKENS + p1];
  const size_t r0 = (size_t)(offs[e0] + p0) * DIM;
  const size_t r1 = (size_t)(offs[e1] + p1) * DIM;

  float v[16];
  {
    const float4* i4 = (const float4*)(in_t + (size_t)t * DIM + lane * 16);
    const uint4* y0 = (const uint4*)(y_buf + r0 + lane * 16);
    const uint4* y1 = (const uint4*)(y_buf + r1 + lane * 16);
#pragma unroll
    for (int i = 0; i < 4; ++i) {
      float4 a = i4[i];
      v[i * 4 + 0] = a.x; v[i * 4 + 1] = a.y; v[i * 4 + 2] = a.z; v[i * 4 + 3] = a.w;
    }
#pragma unroll
    for (int i = 0; i < 2; ++i) {
      uint4 u0 = y0[i];
      uint4 u1 = y1[i];
      const unsigned uw0[4] = {u0.x, u0.y, u0.z, u0.w};
      const unsigned uw1[4] = {u1.x, u1.y, u1.z, u1.w};
#pragma unroll
      for (int k = 0; k < 4; ++k) {
        const int base = i * 8 + k * 2;
        v[base + 0] += w0 * bf2f((unsigned short)(uw0[k] & 0xffff)) +
                       w1 * bf2f((unsigned short)(uw1[k] & 0xffff));
        v[base + 1] += w0 * bf2f((unsigned short)(uw0[k] >> 16)) +
                       w1 * bf2f((unsigned short)(uw1[k] >> 16));
      }
    }
  }

  float sum = 0.f, s2 = 0.f;
#pragma unroll
  for (int i = 0; i < 16; ++i) { sum += v[i]; s2 += v[i] * v[i]; }
#pragma unroll
  for (int sh = 1; sh < 64; sh <<= 1) {
    sum += __shfl_xor(sum, sh, 64);
    s2 += __shfl_xor(s2, sh, 64);
  }
  const float mu = sum * (1.0f / DIM);
  const float var = s2 * (1.0f / DIM) - mu * mu;
  const float rs = rsqrtf(var + 1e-5f);

  float4* w4 = (float4*)(out + (size_t)t * DIM + lane * 16);
#pragma unroll
  for (int i = 0; i < 4; ++i) {
    const int d = lane * 16 + i * 4;
    float4 gg = *(const float4*)(gamma + d);
    float4 bb = *(const float4*)(beta + d);
    float4 o;
    o.x = (v[i * 4 + 0] - mu) * rs * gg.x + bb.x;
    o.y = (v[i * 4 + 1] - mu) * rs * gg.y + bb.y;
    o.z = (v[i * 4 + 2] - mu) * rs * gg.z + bb.z;
    o.w = (v[i * 4 + 3] - mu) * rs * gg.w + bb.w;
    w4[i] = o;
  }
}

extern "C" void kernel_launch(void* const* d_in, const int* in_sizes, int n_in,
                              void* d_out, int out_size, void* d_ws, size_t ws_size,
                              hipStream_t stream) {
  const float* hs    = (const float*)d_in[0];
  const float* in_t  = (const float*)d_in[1];
  const float* gw    = (const float*)d_in[2];
  const float* gb    = (const float*)d_in[3];
  const float* w1    = (const float*)d_in[4];
  const float* b1    = (const float*)d_in[5];
  const float* w2    = (const float*)d_in[6];
  const float* b2    = (const float*)d_in[7];
  const float* gamma = (const float*)d_in[8];
  const float* beta  = (const float*)d_in[9];
  float* out = (float*)d_out;
  char* ws = (char*)d_ws;

  // workspace layout (bytes)
  int* counts            = (int*)(ws + 0);                    // 32
  int* offs              = (int*)(ws + 256);                  // 36
  unsigned int* slotinfo = (unsigned int*)(ws + 512);         // 32 KiB (packed)
  int* nchk              = (int*)(ws + 33280);                // 8
  int* chunks0           = (int*)(ws + 33536);                // <=256 ints
  int* chunks1           = (int*)(ws + 35072);                // <=64 ints
  int* tok_idx           = (int*)(ws + 66048);                // 256 KiB
  float* tok_w           = (float*)(ws + 328192);             // 256 KiB
  unsigned short* hs_bf  = (unsigned short*)(ws + 590336);    // 16 MiB
  unsigned short* w1t    = (unsigned short*)(ws + 17367552);  // 64 MiB [E][F][D]
  unsigned short* w2t    = (unsigned short*)(ws + 84476416);  // 64 MiB [E][D][F]
  unsigned short* h_buf  = (unsigned short*)(ws + 151585280); // 128 MiB [2T][F]
  // y_buf aliases hs_bf + head of w1t: both fully rewritten every call before
  // any reader; y_buf written (MODE1) strictly after their last reader (MODE0).
  unsigned short* y_buf  = (unsigned short*)(ws + 590336);    // 32 MiB [2T][D]

  zero_counts_kernel<<<1, 64, 0, stream>>>(counts);
  router_kernel<<<TOKENS / 4, 256, 0, stream>>>(hs, gw, gb, counts, tok_idx, tok_w,
                                                slotinfo, hs_bf);
  scan_kernel<<<1, 64, 0, stream>>>(counts, offs, nchk, chunks0, chunks1);
  cast_transpose_all<<<16384, 256, 0, stream>>>(w1, w1t, w2, w2t);
  // grids: MODE0 <= ~192 chunks -> 256 slots (grid 4096); MODE1 <= ~64 -> 64 slots (1024)
  moe_gemm<0, DIM, FDIM><<<4096, 256, 0, stream>>>(
      hs_bf, w1t, b1, counts, offs, tok_idx, chunks0, nchk, h_buf);
  moe_gemm<1, FDIM, DIM><<<1024, 256, 0, stream>>>(
      h_buf, w2t, b2, counts, offs, tok_idx, chunks1, nchk, y_buf);
  ln_combine_kernel<<<TOKENS / 4, 256, 0, stream>>>(y_buf, in_t, offs, slotinfo,
                                                    tok_w, gamma, beta, out);
}

// Round 12
// 715.237 us; speedup vs baseline: 1.1456x; 1.1456x over previous
//
#include <hip/hip_runtime.h>

#define TOKENS 8192
#define DIM 1024
#define NEXP 8
#define FDIM 4096

typedef __bf16 bf16x8 __attribute__((ext_vector_type(8)));
typedef float f32x4 __attribute__((ext_vector_type(4)));
typedef float f32x16 __attribute__((ext_vector_type(16)));

__device__ __forceinline__ unsigned short f2bf(float f) {
  unsigned u = __builtin_bit_cast(unsigned, f);
  u += 0x7fffu + ((u >> 16) & 1u);
  return (unsigned short)(u >> 16);
}

__device__ __forceinline__ float bf2f(unsigned short s) {
  unsigned u = (unsigned)s << 16;
  return __builtin_bit_cast(float, u);
}

__device__ __forceinline__ void gload16(const void* g, void* l) {
  __builtin_amdgcn_global_load_lds(
      (const __attribute__((address_space(1))) unsigned int*)g,
      (__attribute__((address_space(3))) unsigned int*)l, 16, 0, 0);
}

// ---------------- router ----------------
__global__ void router_kernel(const float* __restrict__ hs,
                              const float* __restrict__ gw,
                              const float* __restrict__ gb,
                              int* __restrict__ counts,
                              int* __restrict__ tok_idx,
                              float* __restrict__ tok_w,
                              unsigned int* __restrict__ slotinfo,
                              unsigned short* __restrict__ hs_bf) {
  const int lane = threadIdx.x & 63;
  const int wid = threadIdx.x >> 6;
  const int t = blockIdx.x * 4 + wid;
  const float* row = hs + (size_t)t * DIM;

  float x[16];
  const float4* r4 = (const float4*)(row + lane * 16);
#pragma unroll
  for (int i = 0; i < 4; ++i) {
    float4 v = r4[i];
    x[i * 4 + 0] = v.x; x[i * 4 + 1] = v.y; x[i * 4 + 2] = v.z; x[i * 4 + 3] = v.w;
  }

  float acc[8];
#pragma unroll
  for (int e = 0; e < 8; ++e) acc[e] = 0.f;
#pragma unroll
  for (int i = 0; i < 16; ++i) {
    const int d = lane * 16 + i;
    const float4* g4 = (const float4*)(gw + (size_t)d * 8);
    float4 g0 = g4[0], g1 = g4[1];
    const float xv = x[i];
    acc[0] += xv * g0.x; acc[1] += xv * g0.y; acc[2] += xv * g0.z; acc[3] += xv * g0.w;
    acc[4] += xv * g1.x; acc[5] += xv * g1.y; acc[6] += xv * g1.z; acc[7] += xv * g1.w;
  }
#pragma unroll
  for (int sh = 1; sh < 64; sh <<= 1) {
#pragma unroll
    for (int e = 0; e < 8; ++e) acc[e] += __shfl_xor(acc[e], sh, 64);
  }
#pragma unroll
  for (int e = 0; e < 8; ++e) acc[e] += gb[e];

  float mx = acc[0];
#pragma unroll
  for (int e = 1; e < 8; ++e) mx = fmaxf(mx, acc[e]);
  float p[8];
  float sum = 0.f;
#pragma unroll
  for (int e = 0; e < 8; ++e) { p[e] = __expf(acc[e] - mx); sum += p[e]; }
  const float inv = 1.0f / sum;

  int i0 = 0; float b0 = p[0];
#pragma unroll
  for (int e = 1; e < 8; ++e) if (p[e] > b0) { b0 = p[e]; i0 = e; }
  int i1 = -1; float b1v = -1.f;
#pragma unroll
  for (int e = 0; e < 8; ++e) if (e != i0 && p[e] > b1v) { b1v = p[e]; i1 = e; }

  if (lane == 0) {
    int pos0 = atomicAdd(&counts[i0], 1);
    tok_idx[i0 * TOKENS + pos0] = t;
    tok_w[i0 * TOKENS + pos0] = b0 * inv;
    int pos1 = atomicAdd(&counts[i1], 1);
    tok_idx[i1 * TOKENS + pos1] = t;
    tok_w[i1 * TOKENS + pos1] = b1v * inv;
    // pack both slots: e0:3 | p0:13 | e1:3 | p1:13
    slotinfo[t] = ((unsigned)i0 << 29) | ((unsigned)pos0 << 16) |
                  ((unsigned)i1 << 13) | (unsigned)pos1;
  }

  unsigned short us[16];
#pragma unroll
  for (int i = 0; i < 16; ++i) us[i] = f2bf(x[i]);
  uint4 o0, o1;
  o0.x = (unsigned)us[0] | ((unsigned)us[1] << 16);
  o0.y = (unsigned)us[2] | ((unsigned)us[3] << 16);
  o0.z = (unsigned)us[4] | ((unsigned)us[5] << 16);
  o0.w = (unsigned)us[6] | ((unsigned)us[7] << 16);
  o1.x = (unsigned)us[8] | ((unsigned)us[9] << 16);
  o1.y = (unsigned)us[10] | ((unsigned)us[11] << 16);
  o1.z = (unsigned)us[12] | ((unsigned)us[13] << 16);
  o1.w = (unsigned)us[14] | ((unsigned)us[15] << 16);
  uint4* dst = (uint4*)(hs_bf + (size_t)t * DIM + lane * 16);
  dst[0] = o0;
  dst[1] = o1;
}

// ---------------- merged transpose+cast (also zeroes counts in block 0) ----------------
// src[e][R][C] f32 -> dst[e][C][R] bf16 ; blocks [0,8192) = w1, [8192,16384) = w2
__global__ void cast_transpose_all(const float* __restrict__ w1,
                                   unsigned short* __restrict__ w1t,
                                   const float* __restrict__ w2,
                                   unsigned short* __restrict__ w2t,
                                   int* __restrict__ counts) {
  __shared__ float tile[64][65];
  const int L = blockIdx.x;
  if (L == 0 && threadIdx.x < NEXP) counts[threadIdx.x] = 0;  // runs before router
  const float* src;
  unsigned short* dstp;
  int R, C, bi;
  if (L < 8192) { src = w1; dstp = w1t; R = DIM;  C = FDIM; bi = L; }
  else          { src = w2; dstp = w2t; R = FDIM; C = DIM;  bi = L - 8192; }
  const int nx = C >> 6;
  const int e = bi >> 10;
  const int w = bi & 1023;
  const int by = w / nx, bx = w % nx;
  const int r0 = by * 64, c0 = bx * 64;
  const float* s = src + (size_t)e * R * C;
  unsigned int* d = (unsigned int*)(dstp + (size_t)e * R * C);

  // float4 loads: thread covers 4 consecutive cols; 16 rows per iteration
#pragma unroll
  for (int i = 0; i < 4; ++i) {
    const int idx = threadIdx.x + i * 256;
    const int r = idx >> 4;
    const int c4 = (idx & 15) * 4;
    float4 v = *(const float4*)(s + (size_t)(r0 + r) * C + (c0 + c4));
    tile[r][c4 + 0] = v.x; tile[r][c4 + 1] = v.y;
    tile[r][c4 + 2] = v.z; tile[r][c4 + 3] = v.w;
  }
  __syncthreads();
#pragma unroll
  for (int i = 0; i < 8; ++i) {
    const int idx = threadIdx.x + i * 256;
    const int c = idx >> 5;
    const int r = (idx & 31) * 2;
    unsigned pk = (unsigned)f2bf(tile[r][c]) | ((unsigned)f2bf(tile[r + 1][c]) << 16);
    d[((size_t)(c0 + c) * R + (r0 + r)) >> 1] = pk;
  }
}

// ---------------- grouped GEMM: 128x128 tile, BK=32, double-buffered 2x16 KiB LDS ----------------
// R10 structure (distance-1 prefetch, counted vmcnt(4), 4 blocks/CU, mfma_32x32x16)
// with the LDS chunk swizzle widened to s(r) = ((r>>1)&3) ^ ((r>>3)&3): rows
// 0/8/16/24 now land in distinct bank-quads -> <=2-way (free) instead of 4-way.
// Work decode (expert/chunk tables) computed inline from counts; scan kernel gone.
template<int MODE, int K, int N>
__global__ __launch_bounds__(256, 4)
void moe_gemm(const unsigned short* __restrict__ Abase,
              const unsigned short* __restrict__ Bbase,
              const float* __restrict__ bias,
              const int* __restrict__ counts,
              const int* __restrict__ tok_idx,
              unsigned short* __restrict__ dst) {
  constexpr int NS = K / 32;
  constexpr int NQ = (MODE == 0) ? 8 : 2;   // n-chunk groups (ntiles/4)
  __shared__ __align__(16) unsigned char sm[32768];

  // ---- inline work decode: chunk g -> (expert e, m-chunk mc, n-chunk n4) ----
  const int L = blockIdx.x;
  const int xk = L & 7;
  const int tt = L >> 3;
  const int g = (tt >> 4) * 8 + xk;
  const int within = tt & 15;

  int e = 0, mcq = 0, n4 = 0, goff = 0, cnt = 0;
  {
    int accC = 0, accOff = 0;
    bool found = false;
#pragma unroll
    for (int ee = 0; ee < NEXP; ++ee) {
      const int c = counts[ee];
      const int mt = (c + 127) >> 7;
      const int mc4 = (mt + 3) >> 2;
      const int ch = mc4 * NQ;
      if (!found && g < accC + ch) {
        const int local = g - accC;
        e = ee;
        mcq = (local / NQ) * 4;
        n4 = (local % NQ) * 4;
        goff = accOff;
        cnt = c;
        found = true;
      }
      accC += ch;
      accOff += c;
    }
    if (!found) return;
  }
  const int m0 = (mcq + (within >> 2)) * 128;
  if (m0 >= cnt) return;
  const int n0 = (n4 + (within & 3)) * 128;

  const int tid = threadIdx.x;
  const int lane = tid & 63;
  const int wid = tid >> 6;
  const int wm = wid >> 1;   // 0..1 : 64-row M band
  const int wn = wid & 1;    // 0..1 : 64-col N band
  const int l31 = lane & 31;
  const int lh = lane >> 5;  // 0..1 : 8-elem K-half within a 16-wide k-quarter

  // ---- staging source pointers (rows trow, trow+64; pre-swizzled chunk) ----
  // s(r) = ((r>>1)&3) ^ ((r>>3)&3); invariant under +64-row shifts (bits >=6).
  const int trow = tid >> 2;
  const int tswz = (tid & 3) ^ ((trow >> 1) & 3) ^ ((trow >> 3) & 3);
  const unsigned char* Bexp = (const unsigned char*)(Bbase + (size_t)e * K * N);

  int gA0 = m0 + trow;      if (gA0 > cnt - 1) gA0 = cnt - 1;
  int gA1 = m0 + trow + 64; if (gA1 > cnt - 1) gA1 = cnt - 1;
  size_t rowA0, rowA1;
  if (MODE == 0) {
    rowA0 = (size_t)tok_idx[e * TOKENS + gA0] * K;
    rowA1 = (size_t)tok_idx[e * TOKENS + gA1] * K;
  } else {
    rowA0 = (size_t)(goff + gA0) * K;
    rowA1 = (size_t)(goff + gA1) * K;
  }
  const unsigned char* pA0 = (const unsigned char*)(Abase + rowA0) + tswz * 16;
  const unsigned char* pA1 = (const unsigned char*)(Abase + rowA1) + tswz * 16;
  const unsigned char* pB0 = Bexp + (size_t)(n0 + trow) * (K * 2) + tswz * 16;
  const unsigned char* pB1 = Bexp + (size_t)(n0 + trow + 64) * (K * 2) + tswz * 16;

  // ---- LDS read bases for 32x32x16 fragments (within a 16 KiB slot) ----
  // stored chunk for (kq,lh) at row r = (kq*2+lh) ^ s(r); kq=1 addr = kq=0 addr ^ 32.
  const int sw = ((l31 >> 1) & 3) ^ ((l31 >> 3) & 3);
  const int cE = lh ^ sw;
  const int aB = wm * 4096 + l31 * 64 + cE * 16;           // kq0 A base (mb via +2048)
  const int bB = 8192 + wn * 4096 + l31 * 64 + cE * 16;    // kq0 B base (nb via +2048)
  const unsigned char* smc = (const unsigned char*)sm;
  unsigned char* smw = (unsigned char*)sm + tid * 16;

  f32x16 acc[2][2];
#pragma unroll
  for (int mb = 0; mb < 2; ++mb)
#pragma unroll
    for (int nb = 0; nb < 2; ++nb)
#pragma unroll
      for (int r = 0; r < 16; ++r) acc[mb][nb][r] = 0.f;

  // ---- prologue: stage step 0 into slot 0 (4 loads/thread) ----
  gload16(pA0, smw);
  gload16(pA1, smw + 4096);
  gload16(pB0, smw + 8192);
  gload16(pB1, smw + 12288);
  pA0 += 64; pA1 += 64; pB0 += 64; pB1 += 64;

#pragma unroll 1
  for (int st = 0; st < NS; ++st) {
    const int cs = (st & 1) << 14;
    const int ns = ((st + 1) & 1) << 14;
    if (st < NS - 1) {
      // prefetch next step into the other slot (its readers drained at the
      // lgkm(0)+barrier that ended step st-1)
      gload16(pA0, smw + ns);
      gload16(pA1, smw + ns + 4096);
      gload16(pB0, smw + ns + 8192);
      gload16(pB1, smw + ns + 12288);
      pA0 += 64; pA1 += 64; pB0 += 64; pB1 += 64;
      asm volatile("s_waitcnt vmcnt(4)" ::: "memory");  // step st's 4 loads landed
    } else {
      asm volatile("s_waitcnt vmcnt(0)" ::: "memory");
    }
    __builtin_amdgcn_s_barrier();
    __builtin_amdgcn_sched_barrier(0);
#pragma unroll
    for (int kq = 0; kq < 2; ++kq) {
      const int ko = kq << 5;  // chunk-bit XOR: kq1 chunk = kq0 chunk ^ 2
      bf16x8 a0 = *(const bf16x8*)(smc + cs + (aB ^ ko));
      bf16x8 a1 = *(const bf16x8*)(smc + cs + ((aB + 2048) ^ ko));
      bf16x8 b0 = *(const bf16x8*)(smc + cs + (bB ^ ko));
      bf16x8 b1 = *(const bf16x8*)(smc + cs + ((bB + 2048) ^ ko));
      acc[0][0] = __builtin_amdgcn_mfma_f32_32x32x16_bf16(a0, b0, acc[0][0], 0, 0, 0);
      acc[0][1] = __builtin_amdgcn_mfma_f32_32x32x16_bf16(a0, b1, acc[0][1], 0, 0, 0);
      acc[1][0] = __builtin_amdgcn_mfma_f32_32x32x16_bf16(a1, b0, acc[1][0], 0, 0, 0);
      acc[1][1] = __builtin_amdgcn_mfma_f32_32x32x16_bf16(a1, b1, acc[1][1], 0, 0, 0);
    }
    __builtin_amdgcn_sched_barrier(0);
    asm volatile("s_waitcnt lgkmcnt(0)" ::: "memory");
    __builtin_amdgcn_s_barrier();
  }

  // ---- epilogue: C/D map col=lane&31, row=(reg&3)+8*(reg>>2)+4*(lane>>5) ----
#pragma unroll
  for (int nb = 0; nb < 2; ++nb) {
    const int fcol = n0 + wn * 64 + nb * 32 + l31;
    const float bv = bias[e * N + fcol];
#pragma unroll
    for (int mb = 0; mb < 2; ++mb) {
#pragma unroll
      for (int r = 0; r < 16; ++r) {
        const int ml = wm * 64 + mb * 32 + (r & 3) + 8 * (r >> 2) + 4 * lh;
        const int gm = m0 + ml;
        if (gm < cnt) {
          float v = acc[mb][nb][r] + bv;
          if (MODE == 0) {
            const float u = 0.7978845608028654f * (v + 0.044715f * v * v * v);
            const float th = 1.0f - 2.0f / (1.0f + __expf(2.0f * u));
            v = 0.5f * v * (1.0f + th);
          }
          dst[(size_t)(goff + gm) * N + fcol] = f2bf(v);
        }
      }
    }
  }
}

// ---------------- fused combine + residual + layernorm (offs inline) ----------------
__global__ void ln_combine_kernel(const unsigned short* __restrict__ y_buf,
                                  const float* __restrict__ in_t,
                                  const int* __restrict__ counts,
                                  const unsigned int* __restrict__ slotinfo,
                                  const float* __restrict__ tok_w,
                                  const float* __restrict__ gamma,
                                  const float* __restrict__ beta,
                                  float* __restrict__ out) {
  const int lane = threadIdx.x & 63;
  const int wid = threadIdx.x >> 6;
  const int t = blockIdx.x * 4 + wid;

  const unsigned s = slotinfo[t];
  const int e0 = s >> 29, p0 = (s >> 16) & 8191;
  const int e1 = (s >> 13) & 7, p1 = s & 8191;
  int off0 = 0, off1 = 0;
#pragma unroll
  for (int ee = 0; ee < NEXP; ++ee) {
    const int c = counts[ee];
    if (ee < e0) off0 += c;
    if (ee < e1) off1 += c;
  }
  const float w0 = tok_w[e0 * TOKENS + p0];
  const float w1 = tok_w[e1 * TOKENS + p1];
  const size_t r0 = (size_t)(off0 + p0) * DIM;
  const size_t r1 = (size_t)(off1 + p1) * DIM;

  float v[16];
  {
    const float4* i4 = (const float4*)(in_t + (size_t)t * DIM + lane * 16);
    const uint4* y0 = (const uint4*)(y_buf + r0 + lane * 16);
    const uint4* y1 = (const uint4*)(y_buf + r1 + lane * 16);
#pragma unroll
    for (int i = 0; i < 4; ++i) {
      float4 a = i4[i];
      v[i * 4 + 0] = a.x; v[i * 4 + 1] = a.y; v[i * 4 + 2] = a.z; v[i * 4 + 3] = a.w;
    }
#pragma unroll
    for (int i = 0; i < 2; ++i) {
      uint4 u0 = y0[i];
      uint4 u1 = y1[i];
      const unsigned uw0[4] = {u0.x, u0.y, u0.z, u0.w};
      const unsigned uw1[4] = {u1.x, u1.y, u1.z, u1.w};
#pragma unroll
      for (int k = 0; k < 4; ++k) {
        const int base = i * 8 + k * 2;
        v[base + 0] += w0 * bf2f((unsigned short)(uw0[k] & 0xffff)) +
                       w1 * bf2f((unsigned short)(uw1[k] & 0xffff));
        v[base + 1] += w0 * bf2f((unsigned short)(uw0[k] >> 16)) +
                       w1 * bf2f((unsigned short)(uw1[k] >> 16));
      }
    }
  }

  float sum = 0.f, s2 = 0.f;
#pragma unroll
  for (int i = 0; i < 16; ++i) { sum += v[i]; s2 += v[i] * v[i]; }
#pragma unroll
  for (int sh = 1; sh < 64; sh <<= 1) {
    sum += __shfl_xor(sum, sh, 64);
    s2 += __shfl_xor(s2, sh, 64);
  }
  const float mu = sum * (1.0f / DIM);
  const float var = s2 * (1.0f / DIM) - mu * mu;
  const float rs = rsqrtf(var + 1e-5f);

  float4* w4 = (float4*)(out + (size_t)t * DIM + lane * 16);
#pragma unroll
  for (int i = 0; i < 4; ++i) {
    const int d = lane * 16 + i * 4;
    float4 gg = *(const float4*)(gamma + d);
    float4 bb = *(const float4*)(beta + d);
    float4 o;
    o.x = (v[i * 4 + 0] - mu) * rs * gg.x + bb.x;
    o.y = (v[i * 4 + 1] - mu) * rs * gg.y + bb.y;
    o.z = (v[i * 4 + 2] - mu) * rs * gg.z + bb.z;
    o.w = (v[i * 4 + 3] - mu) * rs * gg.w + bb.w;
    w4[i] = o;
  }
}

extern "C" void kernel_launch(void* const* d_in, const int* in_sizes, int n_in,
                              void* d_out, int out_size, void* d_ws, size_t ws_size,
                              hipStream_t stream) {
  const float* hs    = (const float*)d_in[0];
  const float* in_t  = (const float*)d_in[1];
  const float* gw    = (const float*)d_in[2];
  const float* gb    = (const float*)d_in[3];
  const float* w1    = (const float*)d_in[4];
  const float* b1    = (const float*)d_in[5];
  const float* w2    = (const float*)d_in[6];
  const float* b2    = (const float*)d_in[7];
  const float* gamma = (const float*)d_in[8];
  const float* beta  = (const float*)d_in[9];
  float* out = (float*)d_out;
  char* ws = (char*)d_ws;

  // workspace layout (bytes)
  int* counts            = (int*)(ws + 0);                    // 32
  unsigned int* slotinfo = (unsigned int*)(ws + 512);         // 32 KiB (packed)
  int* tok_idx           = (int*)(ws + 66048);                // 256 KiB
  float* tok_w           = (float*)(ws + 328192);             // 256 KiB
  unsigned short* hs_bf  = (unsigned short*)(ws + 590336);    // 16 MiB
  unsigned short* w1t    = (unsigned short*)(ws + 17367552);  // 64 MiB [E][F][D]
  unsigned short* w2t    = (unsigned short*)(ws + 84476416);  // 64 MiB [E][D][F]
  unsigned short* h_buf  = (unsigned short*)(ws + 151585280); // 128 MiB [2T][F]
  // y_buf aliases hs_bf + head of w1t: both fully rewritten every call before
  // any reader; y_buf written (MODE1) strictly after their last reader (MODE0).
  unsigned short* y_buf  = (unsigned short*)(ws + 590336);    // 32 MiB [2T][D]

  cast_transpose_all<<<16384, 256, 0, stream>>>(w1, w1t, w2, w2t, counts);
  router_kernel<<<TOKENS / 4, 256, 0, stream>>>(hs, gw, gb, counts, tok_idx, tok_w,
                                                slotinfo, hs_bf);
  moe_gemm<0, DIM, FDIM><<<6144, 256, 0, stream>>>(
      hs_bf, w1t, b1, counts, tok_idx, h_buf);
  moe_gemm<1, FDIM, DIM><<<2048, 256, 0, stream>>>(
      h_buf, w2t, b2, counts, tok_idx, y_buf);
  ln_combine_kernel<<<TOKENS / 4, 256, 0, stream>>>(y_buf, in_t, counts, slotinfo,
                                                    tok_w, gamma, beta, out);
}

// Round 13
// 707.322 us; speedup vs baseline: 1.1584x; 1.0112x over previous
//
#include <hip/hip_runtime.h>

#define TOKENS 8192
#define DIM 1024
#define NEXP 8
#define FDIM 4096

typedef __bf16 bf16x8 __attribute__((ext_vector_type(8)));
typedef float f32x4 __attribute__((ext_vector_type(4)));
typedef float f32x16 __attribute__((ext_vector_type(16)));

__device__ __forceinline__ unsigned short f2bf(float f) {
  unsigned u = __builtin_bit_cast(unsigned, f);
  u += 0x7fffu + ((u >> 16) & 1u);
  return (unsigned short)(u >> 16);
}

__device__ __forceinline__ float bf2f(unsigned short s) {
  unsigned u = (unsigned)s << 16;
  return __builtin_bit_cast(float, u);
}

__device__ __forceinline__ void gload16(const void* g, void* l) {
  __builtin_amdgcn_global_load_lds(
      (const __attribute__((address_space(1))) unsigned int*)g,
      (__attribute__((address_space(3))) unsigned int*)l, 16, 0, 0);
}

// ---------------- mega kernel: weight transpose+cast (blocks 0..16383) ----------------
// ---------------- + router (blocks 16384..18431), overlapped ----------------
// transpose: src[e][R][C] f32 -> dst[e][C][R] bf16 ; [0,8192)=w1, [8192,16384)=w2.
// router: per token, fp32 gate logits -> softmax -> top-2, cast hs row to bf16.
// counts must be zeroed before launch (hipMemsetAsync on the same stream).
__global__ void prep_kernel(const float* __restrict__ w1,
                            unsigned short* __restrict__ w1t,
                            const float* __restrict__ w2,
                            unsigned short* __restrict__ w2t,
                            const float* __restrict__ hs,
                            const float* __restrict__ gw,
                            const float* __restrict__ gb,
                            int* __restrict__ counts,
                            int* __restrict__ tok_idx,
                            float* __restrict__ tok_w,
                            unsigned int* __restrict__ slotinfo,
                            unsigned short* __restrict__ hs_bf) {
  __shared__ float tile[64][65];
  const int L = blockIdx.x;

  if (L >= 16384) {
    // -------- router part --------
    const int lane = threadIdx.x & 63;
    const int wid = threadIdx.x >> 6;
    const int t = (L - 16384) * 4 + wid;
    const float* row = hs + (size_t)t * DIM;

    float x[16];
    const float4* r4 = (const float4*)(row + lane * 16);
#pragma unroll
    for (int i = 0; i < 4; ++i) {
      float4 v = r4[i];
      x[i * 4 + 0] = v.x; x[i * 4 + 1] = v.y; x[i * 4 + 2] = v.z; x[i * 4 + 3] = v.w;
    }

    float acc[8];
#pragma unroll
    for (int e = 0; e < 8; ++e) acc[e] = 0.f;
#pragma unroll
    for (int i = 0; i < 16; ++i) {
      const int d = lane * 16 + i;
      const float4* g4 = (const float4*)(gw + (size_t)d * 8);
      float4 g0 = g4[0], g1 = g4[1];
      const float xv = x[i];
      acc[0] += xv * g0.x; acc[1] += xv * g0.y; acc[2] += xv * g0.z; acc[3] += xv * g0.w;
      acc[4] += xv * g1.x; acc[5] += xv * g1.y; acc[6] += xv * g1.z; acc[7] += xv * g1.w;
    }
#pragma unroll
    for (int sh = 1; sh < 64; sh <<= 1) {
#pragma unroll
      for (int e = 0; e < 8; ++e) acc[e] += __shfl_xor(acc[e], sh, 64);
    }
#pragma unroll
    for (int e = 0; e < 8; ++e) acc[e] += gb[e];

    float mx = acc[0];
#pragma unroll
    for (int e = 1; e < 8; ++e) mx = fmaxf(mx, acc[e]);
    float p[8];
    float sum = 0.f;
#pragma unroll
    for (int e = 0; e < 8; ++e) { p[e] = __expf(acc[e] - mx); sum += p[e]; }
    const float inv = 1.0f / sum;

    int i0 = 0; float b0 = p[0];
#pragma unroll
    for (int e = 1; e < 8; ++e) if (p[e] > b0) { b0 = p[e]; i0 = e; }
    int i1 = -1; float b1v = -1.f;
#pragma unroll
    for (int e = 0; e < 8; ++e) if (e != i0 && p[e] > b1v) { b1v = p[e]; i1 = e; }

    if (lane == 0) {
      int pos0 = atomicAdd(&counts[i0], 1);
      tok_idx[i0 * TOKENS + pos0] = t;
      tok_w[i0 * TOKENS + pos0] = b0 * inv;
      int pos1 = atomicAdd(&counts[i1], 1);
      tok_idx[i1 * TOKENS + pos1] = t;
      tok_w[i1 * TOKENS + pos1] = b1v * inv;
      // pack both slots: e0:3 | p0:13 | e1:3 | p1:13
      slotinfo[t] = ((unsigned)i0 << 29) | ((unsigned)pos0 << 16) |
                    ((unsigned)i1 << 13) | (unsigned)pos1;
    }

    unsigned short us[16];
#pragma unroll
    for (int i = 0; i < 16; ++i) us[i] = f2bf(x[i]);
    uint4 o0, o1;
    o0.x = (unsigned)us[0] | ((unsigned)us[1] << 16);
    o0.y = (unsigned)us[2] | ((unsigned)us[3] << 16);
    o0.z = (unsigned)us[4] | ((unsigned)us[5] << 16);
    o0.w = (unsigned)us[6] | ((unsigned)us[7] << 16);
    o1.x = (unsigned)us[8] | ((unsigned)us[9] << 16);
    o1.y = (unsigned)us[10] | ((unsigned)us[11] << 16);
    o1.z = (unsigned)us[12] | ((unsigned)us[13] << 16);
    o1.w = (unsigned)us[14] | ((unsigned)us[15] << 16);
    uint4* dst = (uint4*)(hs_bf + (size_t)t * DIM + lane * 16);
    dst[0] = o0;
    dst[1] = o1;
    return;
  }

  // -------- transpose part --------
  const float* src;
  unsigned short* dstp;
  int R, C, bi;
  if (L < 8192) { src = w1; dstp = w1t; R = DIM;  C = FDIM; bi = L; }
  else          { src = w2; dstp = w2t; R = FDIM; C = DIM;  bi = L - 8192; }
  const int nx = C >> 6;
  const int e = bi >> 10;
  const int w = bi & 1023;
  const int by = w / nx, bx = w % nx;
  const int r0 = by * 64, c0 = bx * 64;
  const float* s = src + (size_t)e * R * C;
  unsigned int* d = (unsigned int*)(dstp + (size_t)e * R * C);

  // float4 loads: thread covers 4 consecutive cols; 16 rows per iteration
#pragma unroll
  for (int i = 0; i < 4; ++i) {
    const int idx = threadIdx.x + i * 256;
    const int r = idx >> 4;
    const int c4 = (idx & 15) * 4;
    float4 v = *(const float4*)(s + (size_t)(r0 + r) * C + (c0 + c4));
    tile[r][c4 + 0] = v.x; tile[r][c4 + 1] = v.y;
    tile[r][c4 + 2] = v.z; tile[r][c4 + 3] = v.w;
  }
  __syncthreads();
#pragma unroll
  for (int i = 0; i < 8; ++i) {
    const int idx = threadIdx.x + i * 256;
    const int c = idx >> 5;
    const int r = (idx & 31) * 2;
    unsigned pk = (unsigned)f2bf(tile[r][c]) | ((unsigned)f2bf(tile[r + 1][c]) << 16);
    d[((size_t)(c0 + c) * R + (r0 + r)) >> 1] = pk;
  }
}

// ---------------- grouped GEMM: 128x128 tile, BK=32, double-buffered 2x16 KiB LDS ----------------
// R12 structure: distance-1 prefetch, counted vmcnt(4), 4 blocks/CU, mfma_32x32x16.
// Work decode computed inline from counts (no scan kernel).
template<int MODE, int K, int N>
__global__ __launch_bounds__(256, 4)
void moe_gemm(const unsigned short* __restrict__ Abase,
              const unsigned short* __restrict__ Bbase,
              const float* __restrict__ bias,
              const int* __restrict__ counts,
              const int* __restrict__ tok_idx,
              unsigned short* __restrict__ dst) {
  constexpr int NS = K / 32;
  constexpr int NQ = (MODE == 0) ? 8 : 2;   // n-chunk groups (ntiles/4)
  __shared__ __align__(16) unsigned char sm[32768];

  // ---- inline work decode: chunk g -> (expert e, m-chunk mc, n-chunk n4) ----
  const int L = blockIdx.x;
  const int xk = L & 7;
  const int tt = L >> 3;
  const int g = (tt >> 4) * 8 + xk;
  const int within = tt & 15;

  int e = 0, mcq = 0, n4 = 0, goff = 0, cnt = 0;
  {
    int accC = 0, accOff = 0;
    bool found = false;
#pragma unroll
    for (int ee = 0; ee < NEXP; ++ee) {
      const int c = counts[ee];
      const int mt = (c + 127) >> 7;
      const int mc4 = (mt + 3) >> 2;
      const int ch = mc4 * NQ;
      if (!found && g < accC + ch) {
        const int local = g - accC;
        e = ee;
        mcq = (local / NQ) * 4;
        n4 = (local % NQ) * 4;
        goff = accOff;
        cnt = c;
        found = true;
      }
      accC += ch;
      accOff += c;
    }
    if (!found) return;
  }
  const int m0 = (mcq + (within >> 2)) * 128;
  if (m0 >= cnt) return;
  const int n0 = (n4 + (within & 3)) * 128;

  const int tid = threadIdx.x;
  const int lane = tid & 63;
  const int wid = tid >> 6;
  const int wm = wid >> 1;   // 0..1 : 64-row M band
  const int wn = wid & 1;    // 0..1 : 64-col N band
  const int l31 = lane & 31;
  const int lh = lane >> 5;  // 0..1 : 8-elem K-half within a 16-wide k-quarter

  // ---- staging source pointers (rows trow, trow+64; pre-swizzled chunk) ----
  const int trow = tid >> 2;
  const int tswz = (tid & 3) ^ ((trow >> 1) & 3) ^ ((trow >> 3) & 3);
  const unsigned char* Bexp = (const unsigned char*)(Bbase + (size_t)e * K * N);

  int gA0 = m0 + trow;      if (gA0 > cnt - 1) gA0 = cnt - 1;
  int gA1 = m0 + trow + 64; if (gA1 > cnt - 1) gA1 = cnt - 1;
  size_t rowA0, rowA1;
  if (MODE == 0) {
    rowA0 = (size_t)tok_idx[e * TOKENS + gA0] * K;
    rowA1 = (size_t)tok_idx[e * TOKENS + gA1] * K;
  } else {
    rowA0 = (size_t)(goff + gA0) * K;
    rowA1 = (size_t)(goff + gA1) * K;
  }
  const unsigned char* pA0 = (const unsigned char*)(Abase + rowA0) + tswz * 16;
  const unsigned char* pA1 = (const unsigned char*)(Abase + rowA1) + tswz * 16;
  const unsigned char* pB0 = Bexp + (size_t)(n0 + trow) * (K * 2) + tswz * 16;
  const unsigned char* pB1 = Bexp + (size_t)(n0 + trow + 64) * (K * 2) + tswz * 16;

  // ---- LDS read bases for 32x32x16 fragments (within a 16 KiB slot) ----
  const int sw = ((l31 >> 1) & 3) ^ ((l31 >> 3) & 3);
  const int cE = lh ^ sw;
  const int aB = wm * 4096 + l31 * 64 + cE * 16;           // kq0 A base (mb via +2048)
  const int bB = 8192 + wn * 4096 + l31 * 64 + cE * 16;    // kq0 B base (nb via +2048)
  const unsigned char* smc = (const unsigned char*)sm;
  unsigned char* smw = (unsigned char*)sm + tid * 16;

  f32x16 acc[2][2];
#pragma unroll
  for (int mb = 0; mb < 2; ++mb)
#pragma unroll
    for (int nb = 0; nb < 2; ++nb)
#pragma unroll
      for (int r = 0; r < 16; ++r) acc[mb][nb][r] = 0.f;

  // ---- prologue: stage step 0 into slot 0 (4 loads/thread) ----
  gload16(pA0, smw);
  gload16(pA1, smw + 4096);
  gload16(pB0, smw + 8192);
  gload16(pB1, smw + 12288);
  pA0 += 64; pA1 += 64; pB0 += 64; pB1 += 64;

#pragma unroll 1
  for (int st = 0; st < NS; ++st) {
    const int cs = (st & 1) << 14;
    const int ns = ((st + 1) & 1) << 14;
    if (st < NS - 1) {
      // prefetch next step into the other slot (its readers drained at the
      // lgkm(0)+barrier that ended step st-1)
      gload16(pA0, smw + ns);
      gload16(pA1, smw + ns + 4096);
      gload16(pB0, smw + ns + 8192);
      gload16(pB1, smw + ns + 12288);
      pA0 += 64; pA1 += 64; pB0 += 64; pB1 += 64;
      asm volatile("s_waitcnt vmcnt(4)" ::: "memory");  // step st's 4 loads landed
    } else {
      asm volatile("s_waitcnt vmcnt(0)" ::: "memory");
    }
    __builtin_amdgcn_s_barrier();
    __builtin_amdgcn_sched_barrier(0);
#pragma unroll
    for (int kq = 0; kq < 2; ++kq) {
      const int ko = kq << 5;  // chunk-bit XOR: kq1 chunk = kq0 chunk ^ 2
      bf16x8 a0 = *(const bf16x8*)(smc + cs + (aB ^ ko));
      bf16x8 a1 = *(const bf16x8*)(smc + cs + ((aB + 2048) ^ ko));
      bf16x8 b0 = *(const bf16x8*)(smc + cs + (bB ^ ko));
      bf16x8 b1 = *(const bf16x8*)(smc + cs + ((bB + 2048) ^ ko));
      acc[0][0] = __builtin_amdgcn_mfma_f32_32x32x16_bf16(a0, b0, acc[0][0], 0, 0, 0);
      acc[0][1] = __builtin_amdgcn_mfma_f32_32x32x16_bf16(a0, b1, acc[0][1], 0, 0, 0);
      acc[1][0] = __builtin_amdgcn_mfma_f32_32x32x16_bf16(a1, b0, acc[1][0], 0, 0, 0);
      acc[1][1] = __builtin_amdgcn_mfma_f32_32x32x16_bf16(a1, b1, acc[1][1], 0, 0, 0);
    }
    __builtin_amdgcn_sched_barrier(0);
    asm volatile("s_waitcnt lgkmcnt(0)" ::: "memory");
    __builtin_amdgcn_s_barrier();
  }

  // ---- epilogue: C/D map col=lane&31, row=(reg&3)+8*(reg>>2)+4*(lane>>5) ----
#pragma unroll
  for (int nb = 0; nb < 2; ++nb) {
    const int fcol = n0 + wn * 64 + nb * 32 + l31;
    const float bv = bias[e * N + fcol];
#pragma unroll
    for (int mb = 0; mb < 2; ++mb) {
#pragma unroll
      for (int r = 0; r < 16; ++r) {
        const int ml = wm * 64 + mb * 32 + (r & 3) + 8 * (r >> 2) + 4 * lh;
        const int gm = m0 + ml;
        if (gm < cnt) {
          float v = acc[mb][nb][r] + bv;
          if (MODE == 0) {
            const float u = 0.7978845608028654f * (v + 0.044715f * v * v * v);
            const float th = 1.0f - 2.0f / (1.0f + __expf(2.0f * u));
            v = 0.5f * v * (1.0f + th);
          }
          dst[(size_t)(goff + gm) * N + fcol] = f2bf(v);
        }
      }
    }
  }
}

// ---------------- fused combine + residual + layernorm (offs inline) ----------------
__global__ void ln_combine_kernel(const unsigned short* __restrict__ y_buf,
                                  const float* __restrict__ in_t,
                                  const int* __restrict__ counts,
                                  const unsigned int* __restrict__ slotinfo,
                                  const float* __restrict__ tok_w,
                                  const float* __restrict__ gamma,
                                  const float* __restrict__ beta,
                                  float* __restrict__ out) {
  const int lane = threadIdx.x & 63;
  const int wid = threadIdx.x >> 6;
  const int t = blockIdx.x * 4 + wid;

  const unsigned s = slotinfo[t];
  const int e0 = s >> 29, p0 = (s >> 16) & 8191;
  const int e1 = (s >> 13) & 7, p1 = s & 8191;
  int off0 = 0, off1 = 0;
#pragma unroll
  for (int ee = 0; ee < NEXP; ++ee) {
    const int c = counts[ee];
    if (ee < e0) off0 += c;
    if (ee < e1) off1 += c;
  }
  const float w0 = tok_w[e0 * TOKENS + p0];
  const float w1 = tok_w[e1 * TOKENS + p1];
  const size_t r0 = (size_t)(off0 + p0) * DIM;
  const size_t r1 = (size_t)(off1 + p1) * DIM;

  float v[16];
  {
    const float4* i4 = (const float4*)(in_t + (size_t)t * DIM + lane * 16);
    const uint4* y0 = (const uint4*)(y_buf + r0 + lane * 16);
    const uint4* y1 = (const uint4*)(y_buf + r1 + lane * 16);
#pragma unroll
    for (int i = 0; i < 4; ++i) {
      float4 a = i4[i];
      v[i * 4 + 0] = a.x; v[i * 4 + 1] = a.y; v[i * 4 + 2] = a.z; v[i * 4 + 3] = a.w;
    }
#pragma unroll
    for (int i = 0; i < 2; ++i) {
      uint4 u0 = y0[i];
      uint4 u1 = y1[i];
      const unsigned uw0[4] = {u0.x, u0.y, u0.z, u0.w};
      const unsigned uw1[4] = {u1.x, u1.y, u1.z, u1.w};
#pragma unroll
      for (int k = 0; k < 4; ++k) {
        const int base = i * 8 + k * 2;
        v[base + 0] += w0 * bf2f((unsigned short)(uw0[k] & 0xffff)) +
                       w1 * bf2f((unsigned short)(uw1[k] & 0xffff));
        v[base + 1] += w0 * bf2f((unsigned short)(uw0[k] >> 16)) +
                       w1 * bf2f((unsigned short)(uw1[k] >> 16));
      }
    }
  }

  float sum = 0.f, s2 = 0.f;
#pragma unroll
  for (int i = 0; i < 16; ++i) { sum += v[i]; s2 += v[i] * v[i]; }
#pragma unroll
  for (int sh = 1; sh < 64; sh <<= 1) {
    sum += __shfl_xor(sum, sh, 64);
    s2 += __shfl_xor(s2, sh, 64);
  }
  const float mu = sum * (1.0f / DIM);
  const float var = s2 * (1.0f / DIM) - mu * mu;
  const float rs = rsqrtf(var + 1e-5f);

  float4* w4 = (float4*)(out + (size_t)t * DIM + lane * 16);
#pragma unroll
  for (int i = 0; i < 4; ++i) {
    const int d = lane * 16 + i * 4;
    float4 gg = *(const float4*)(gamma + d);
    float4 bb = *(const float4*)(beta + d);
    float4 o;
    o.x = (v[i * 4 + 0] - mu) * rs * gg.x + bb.x;
    o.y = (v[i * 4 + 1] - mu) * rs * gg.y + bb.y;
    o.z = (v[i * 4 + 2] - mu) * rs * gg.z + bb.z;
    o.w = (v[i * 4 + 3] - mu) * rs * gg.w + bb.w;
    w4[i] = o;
  }
}

extern "C" void kernel_launch(void* const* d_in, const int* in_sizes, int n_in,
                              void* d_out, int out_size, void* d_ws, size_t ws_size,
                              hipStream_t stream) {
  const float* hs    = (const float*)d_in[0];
  const float* in_t  = (const float*)d_in[1];
  const float* gw    = (const float*)d_in[2];
  const float* gb    = (const float*)d_in[3];
  const float* w1    = (const float*)d_in[4];
  const float* b1    = (const float*)d_in[5];
  const float* w2    = (const float*)d_in[6];
  const float* b2    = (const float*)d_in[7];
  const float* gamma = (const float*)d_in[8];
  const float* beta  = (const float*)d_in[9];
  float* out = (float*)d_out;
  char* ws = (char*)d_ws;

  // workspace layout (bytes)
  int* counts            = (int*)(ws + 0);                    // 32
  unsigned int* slotinfo = (unsigned int*)(ws + 512);         // 32 KiB (packed)
  int* tok_idx           = (int*)(ws + 66048);                // 256 KiB
  float* tok_w           = (float*)(ws + 328192);             // 256 KiB
  unsigned short* hs_bf  = (unsigned short*)(ws + 590336);    // 16 MiB
  unsigned short* w1t    = (unsigned short*)(ws + 17367552);  // 64 MiB [E][F][D]
  unsigned short* w2t    = (unsigned short*)(ws + 84476416);  // 64 MiB [E][D][F]
  unsigned short* h_buf  = (unsigned short*)(ws + 151585280); // 128 MiB [2T][F]
  // y_buf aliases hs_bf + head of w1t: both fully rewritten every call before
  // any reader; y_buf written (MODE1) strictly after their last reader (MODE0).
  unsigned short* y_buf  = (unsigned short*)(ws + 590336);    // 32 MiB [2T][D]

  hipMemsetAsync(counts, 0, NEXP * sizeof(int), stream);
  prep_kernel<<<18432, 256, 0, stream>>>(w1, w1t, w2, w2t,
                                         hs, gw, gb, counts, tok_idx, tok_w,
                                         slotinfo, hs_bf);
  moe_gemm<0, DIM, FDIM><<<6144, 256, 0, stream>>>(
      hs_bf, w1t, b1, counts, tok_idx, h_buf);
  moe_gemm<1, FDIM, DIM><<<2048, 256, 0, stream>>>(
      h_buf, w2t, b2, counts, tok_idx, y_buf);
  ln_combine_kernel<<<TOKENS / 4, 256, 0, stream>>>(y_buf, in_t, counts, slotinfo,
                                                    tok_w, gamma, beta, out);
}